// Round 1
// baseline (637.911 us; speedup 1.0000x reference)
//
#include <hip/hip_runtime.h>
#include <hip/hip_bf16.h>
#include <cstdint>

typedef short short8 __attribute__((ext_vector_type(8)));
typedef __bf16 bf16x8 __attribute__((ext_vector_type(8)));
typedef float float4v __attribute__((ext_vector_type(4)));

#define NKV 8
#define G 8
#define D 64
#define NH 64          // NKV*G
#define BB 2           // batch
#define S 1024
#define H 4096
#define MROWS (BB*S)   // 2048
#define NQKV (H + 2*NKV*D)   // 5120

__device__ __forceinline__ unsigned short f2b(float f) {
    union { float f; uint32_t u; } v; v.f = f;
    uint32_t u = v.u;
    uint32_t r = (u + 0x7FFFu + ((u >> 16) & 1u)) >> 16;
    return (unsigned short)r;
}
__device__ __forceinline__ float b2f(unsigned short b) {
    union { float f; uint32_t u; } v; v.u = ((uint32_t)b) << 16;
    return v.f;
}

// ---------------- fp32 -> bf16 conversion ----------------
__global__ void cvt_f32_bf16(const float* __restrict__ src, unsigned short* __restrict__ dst, int n) {
    int i = (blockIdx.x * blockDim.x + threadIdx.x) * 4;
    int stride = gridDim.x * blockDim.x * 4;
    for (; i < n; i += stride) {
        float4 f = *(const float4*)(src + i);
        ushort4 o;
        o.x = f2b(f.x); o.y = f2b(f.y); o.z = f2b(f.z); o.w = f2b(f.w);
        *(ushort4*)(dst + i) = o;
    }
}

// ---------------- NT GEMM: C[M,N] = A[M,K] * W[N,K]^T, bf16 in, fp32 acc ----------------
// 128x128 block tile, BK=32, 4 waves (2x2 of 64x64), 16x16x32 MFMA.
template <bool BF16_OUT>
__global__ __launch_bounds__(256) void gemm_nt(
    const unsigned short* __restrict__ A, const unsigned short* __restrict__ W,
    void* __restrict__ Cv, int M, int N, int K) {
    __shared__ unsigned short As[128 * 40];
    __shared__ unsigned short Bs[128 * 40];
    const int bm = blockIdx.y * 128, bn = blockIdx.x * 128;
    const int tid = threadIdx.x;
    const int w = tid >> 6, lane = tid & 63;
    const int col = lane & 15, quad = lane >> 4;
    const int wm = (w & 1) * 64, wn = (w >> 1) * 64;

    float4v acc[4][4];
    float4v zero4 = {0.f, 0.f, 0.f, 0.f};
#pragma unroll
    for (int i = 0; i < 4; i++)
#pragma unroll
        for (int j = 0; j < 4; j++) acc[i][j] = zero4;

    for (int k0 = 0; k0 < K; k0 += 32) {
        __syncthreads();
#pragma unroll
        for (int i = 0; i < 2; i++) {
            int c = i * 256 + tid;
            int row = c >> 2, cc = (c & 3) * 8;
            *(short8*)&As[row * 40 + cc] = *(const short8*)&A[(size_t)(bm + row) * K + k0 + cc];
            *(short8*)&Bs[row * 40 + cc] = *(const short8*)&W[(size_t)(bn + row) * K + k0 + cc];
        }
        __syncthreads();
        bf16x8 af[4], bf[4];
#pragma unroll
        for (int i = 0; i < 4; i++) af[i] = *(const bf16x8*)&As[(wm + i * 16 + col) * 40 + quad * 8];
#pragma unroll
        for (int j = 0; j < 4; j++) bf[j] = *(const bf16x8*)&Bs[(wn + j * 16 + col) * 40 + quad * 8];
#pragma unroll
        for (int i = 0; i < 4; i++)
#pragma unroll
            for (int j = 0; j < 4; j++)
                acc[i][j] = __builtin_amdgcn_mfma_f32_16x16x32_bf16(af[i], bf[j], acc[i][j], 0, 0, 0);
    }

#pragma unroll
    for (int i = 0; i < 4; i++) {
#pragma unroll
        for (int j = 0; j < 4; j++) {
#pragma unroll
            for (int r = 0; r < 4; r++) {
                int grow = bm + wm + i * 16 + quad * 4 + r;
                int gcol = bn + wn + j * 16 + col;
                if (BF16_OUT)
                    ((unsigned short*)Cv)[(size_t)grow * N + gcol] = f2b(acc[i][j][r]);
                else
                    ((float*)Cv)[(size_t)grow * N + gcol] = acc[i][j][r];
            }
        }
    }
}

// ---------------- RoPE + scatter to head-major Q/K/V ----------------
__global__ void rope_scatter(const unsigned short* __restrict__ qkv,
                             const float* __restrict__ cosb, const float* __restrict__ sinb,
                             unsigned short* __restrict__ qa, unsigned short* __restrict__ ka,
                             unsigned short* __restrict__ va) {
    int idx = blockIdx.x * blockDim.x + threadIdx.x;
    const int total = MROWS * NQKV;
    const int stride = gridDim.x * blockDim.x;
    for (; idx < total; idx += stride) {
        int row = idx / NQKV, o = idx - row * NQKV;
        int b = row >> 10, s = row & 1023;
        float x = b2f(qkv[idx]);
        if (o < H) {
            int kv = o >> 9, g = (o >> 6) & 7, d = o & 63;
            int po = (d < 32) ? idx + 32 : idx - 32;
            float partner = b2f(qkv[po]);
            float rot = (d < 32) ? -partner : partner;
            float y = x * cosb[s * 64 + d] + rot * sinb[s * 64 + d];
            int h = b * 64 + kv * 8 + g;
            qa[(size_t)h * (S * D) + s * 64 + d] = f2b(y);
        } else if (o < H + 512) {
            int o2 = o - H;
            int kv = o2 >> 6, d = o2 & 63;
            int po = (d < 32) ? idx + 32 : idx - 32;
            float partner = b2f(qkv[po]);
            float rot = (d < 32) ? -partner : partner;
            float y = x * cosb[s * 64 + d] + rot * sinb[s * 64 + d];
            ka[(size_t)(b * NKV + kv) * (S * D) + s * 64 + d] = f2b(y);
        } else {
            int o2 = o - H - 512;
            int kv = o2 >> 6, d = o2 & 63;
            va[(size_t)(b * NKV + kv) * (S * D) + s * 64 + d] = qkv[idx];
        }
    }
}

// ---------------- Flash attention: block = (head, 64-row Q tile) ----------------
__global__ __launch_bounds__(256) void attn_kernel(
    const unsigned short* __restrict__ qa, const unsigned short* __restrict__ ka,
    const unsigned short* __restrict__ va, unsigned short* __restrict__ out) {
    __shared__ unsigned short Ks[64 * 72];
    __shared__ unsigned short Vt[64 * 72];
    __shared__ unsigned short Ps[4 * 16 * 72];
    const int qt = blockIdx.x;   // 0..15
    const int h  = blockIdx.y;   // 0..127
    const int b = h >> 6, kvh = (h >> 3) & 7;
    const int tid = threadIdx.x, w = tid >> 6, lane = tid & 63;
    const int col = lane & 15, quad = lane >> 4;
    const int qb = qt * 64;
    const unsigned short* Q = qa + (size_t)h * (S * D) + (size_t)qb * D;
    const unsigned short* K = ka + (size_t)(b * NKV + kvh) * (S * D);
    const unsigned short* V = va + (size_t)(b * NKV + kvh) * (S * D);

    bf16x8 aq[2];
#pragma unroll
    for (int c = 0; c < 2; c++)
        aq[c] = *(const bf16x8*)&Q[(w * 16 + col) * 64 + c * 32 + quad * 8];

    float m_run[4], l_run[4];
    float4v o_acc[4];
    float4v zero4 = {0.f, 0.f, 0.f, 0.f};
#pragma unroll
    for (int r = 0; r < 4; r++) { m_run[r] = -1e30f; l_run[r] = 0.f; }
#pragma unroll
    for (int dg = 0; dg < 4; dg++) o_acc[dg] = zero4;

    for (int kt = 0; kt <= qt; kt++) {
        const int kb = kt * 64;
        __syncthreads();
        // stage K [key][d] and V^T [d][key]
#pragma unroll
        for (int i = 0; i < 2; i++) {
            int c = i * 256 + tid;
            int krow = c >> 3, cc = (c & 7) * 8;
            *(short8*)&Ks[krow * 72 + cc] = *(const short8*)&K[(kb + krow) * 64 + cc];
            short8 vv = *(const short8*)&V[(kb + krow) * 64 + cc];
#pragma unroll
            for (int j = 0; j < 8; j++) Vt[(cc + j) * 72 + krow] = (unsigned short)vv[j];
        }
        __syncthreads();
        // scores: Q(16x64) * K_tile^T -> 16x64
        float4v sc[4];
#pragma unroll
        for (int n16 = 0; n16 < 4; n16++) {
            bf16x8 bk0 = *(const bf16x8*)&Ks[(n16 * 16 + col) * 72 + quad * 8];
            bf16x8 bk1 = *(const bf16x8*)&Ks[(n16 * 16 + col) * 72 + 32 + quad * 8];
            float4v a = __builtin_amdgcn_mfma_f32_16x16x32_bf16(aq[0], bk0, zero4, 0, 0, 0);
            sc[n16] = __builtin_amdgcn_mfma_f32_16x16x32_bf16(aq[1], bk1, a, 0, 0, 0);
        }
        // scale + causal mask
#pragma unroll
        for (int n16 = 0; n16 < 4; n16++) {
            int key = kb + n16 * 16 + col;
#pragma unroll
            for (int r = 0; r < 4; r++) {
                int qrow = qb + w * 16 + quad * 4 + r;
                float sv = sc[n16][r] * 0.125f;
                sc[n16][r] = (key <= qrow) ? sv : -1e30f;
            }
        }
        // online softmax update (per row r, reduce across 16 lanes of quad)
#pragma unroll
        for (int r = 0; r < 4; r++) {
            float mx = fmaxf(fmaxf(sc[0][r], sc[1][r]), fmaxf(sc[2][r], sc[3][r]));
#pragma unroll
            for (int off = 1; off < 16; off <<= 1) mx = fmaxf(mx, __shfl_xor(mx, off));
            float mnew = fmaxf(m_run[r], mx);
            float alpha = __expf(m_run[r] - mnew);
            float rsum = 0.f;
#pragma unroll
            for (int n16 = 0; n16 < 4; n16++) {
                float p = __expf(sc[n16][r] - mnew);
                sc[n16][r] = p;
                rsum += p;
            }
#pragma unroll
            for (int off = 1; off < 16; off <<= 1) rsum += __shfl_xor(rsum, off);
            l_run[r] = l_run[r] * alpha + rsum;
            m_run[r] = mnew;
#pragma unroll
            for (int dg = 0; dg < 4; dg++) o_acc[dg][r] *= alpha;
        }
        // write P (C/D layout) to LDS as bf16
#pragma unroll
        for (int n16 = 0; n16 < 4; n16++)
#pragma unroll
            for (int r = 0; r < 4; r++)
                Ps[w * 1152 + (quad * 4 + r) * 72 + n16 * 16 + col] = f2b(sc[n16][r]);
        __syncthreads();
        // PV: P(16x64) * V(64x64); A-operand from LDS, B from V^T
        bf16x8 ap[2];
#pragma unroll
        for (int c = 0; c < 2; c++)
            ap[c] = *(const bf16x8*)&Ps[w * 1152 + col * 72 + c * 32 + quad * 8];
#pragma unroll
        for (int dg = 0; dg < 4; dg++) {
            bf16x8 bv0 = *(const bf16x8*)&Vt[(dg * 16 + col) * 72 + quad * 8];
            bf16x8 bv1 = *(const bf16x8*)&Vt[(dg * 16 + col) * 72 + 32 + quad * 8];
            float4v t = __builtin_amdgcn_mfma_f32_16x16x32_bf16(ap[0], bv0, o_acc[dg], 0, 0, 0);
            o_acc[dg] = __builtin_amdgcn_mfma_f32_16x16x32_bf16(ap[1], bv1, t, 0, 0, 0);
        }
    }
    // epilogue: normalize and store to attn_out [b*S+s][ (h&63)*64 + d ]
    const int hcol = (h & 63) * 64;
#pragma unroll
    for (int r = 0; r < 4; r++) {
        float inv = 1.f / l_run[r];
        int grow = b * S + qb + w * 16 + quad * 4 + r;
#pragma unroll
        for (int dg = 0; dg < 4; dg++)
            out[(size_t)grow * H + hcol + dg * 16 + col] = f2b(o_acc[dg][r] * inv);
    }
}

extern "C" void kernel_launch(void* const* d_in, const int* in_sizes, int n_in,
                              void* d_out, int out_size, void* d_ws, size_t ws_size,
                              hipStream_t stream) {
    const float* hs   = (const float*)d_in[0];
    // d_in[1] alibi, d_in[2] attention_mask: unused by reference (zeros, never referenced)
    const float* cosb = (const float*)d_in[3];
    const float* sinb = (const float*)d_in[4];
    const float* wq   = (const float*)d_in[5];
    const float* wk   = (const float*)d_in[6];
    const float* wv   = (const float*)d_in[7];
    const float* wd   = (const float*)d_in[8];

    char* p = (char*)d_ws;
    auto alloc = [&](size_t bytes) { char* r = p; p += (bytes + 255) & ~(size_t)255; return r; };
    unsigned short* wqkv_b = (unsigned short*)alloc((size_t)NQKV * H * 2);   // 40 MB
    unsigned short* wd_b   = (unsigned short*)alloc((size_t)H * H * 2);      // 32 MB
    unsigned short* qkv    = (unsigned short*)alloc((size_t)MROWS * NQKV * 2); // 20 MB
    unsigned short* qa     = (unsigned short*)alloc((size_t)BB * NH * S * D * 2); // 16 MB
    unsigned short* ka     = (unsigned short*)alloc((size_t)BB * NKV * S * D * 2); // 2 MB
    unsigned short* va     = (unsigned short*)alloc((size_t)BB * NKV * S * D * 2); // 2 MB
    unsigned short* hs_b   = (unsigned short*)alloc((size_t)MROWS * H * 2);  // 16 MB (reused as attn out)
    unsigned short* ao     = hs_b;  // alias: hs_b consumed by GEMM1 before attn writes ao

    cvt_f32_bf16<<<2048, 256, 0, stream>>>(hs, hs_b, MROWS * H);
    cvt_f32_bf16<<<2048, 256, 0, stream>>>(wq, wqkv_b, H * H);
    cvt_f32_bf16<<<1024, 256, 0, stream>>>(wk, wqkv_b + (size_t)H * H, 512 * H);
    cvt_f32_bf16<<<1024, 256, 0, stream>>>(wv, wqkv_b + (size_t)H * H + (size_t)512 * H, 512 * H);
    cvt_f32_bf16<<<2048, 256, 0, stream>>>(wd, wd_b, H * H);

    gemm_nt<true><<<dim3(NQKV / 128, MROWS / 128), 256, 0, stream>>>(hs_b, wqkv_b, qkv, MROWS, NQKV, H);
    rope_scatter<<<4096, 256, 0, stream>>>(qkv, cosb, sinb, qa, ka, va);
    attn_kernel<<<dim3(16, 128), 256, 0, stream>>>(qa, ka, va, ao);
    gemm_nt<false><<<dim3(H / 128, MROWS / 128), 256, 0, stream>>>(ao, wd_b, d_out, MROWS, H, H);
}

// Round 2
// 524.359 us; speedup vs baseline: 1.2166x; 1.2166x over previous
//
#include <hip/hip_runtime.h>
#include <hip/hip_bf16.h>
#include <cstdint>

typedef short short8 __attribute__((ext_vector_type(8)));
typedef __bf16 bf16x8 __attribute__((ext_vector_type(8)));
typedef float float4v __attribute__((ext_vector_type(4)));

#define NKV 8
#define G 8
#define D 64
#define NH 64          // NKV*G
#define BB 2           // batch
#define S 1024
#define H 4096
#define MROWS (BB*S)   // 2048
#define NQKV (H + 2*NKV*D)   // 5120

__device__ __forceinline__ unsigned short f2b(float f) {
    union { float f; uint32_t u; } v; v.f = f;
    uint32_t u = v.u;
    uint32_t r = (u + 0x7FFFu + ((u >> 16) & 1u)) >> 16;
    return (unsigned short)r;
}
__device__ __forceinline__ float b2f(unsigned short b) {
    union { float f; uint32_t u; } v; v.u = ((uint32_t)b) << 16;
    return v.f;
}

__device__ __forceinline__ void gload_lds16(const unsigned short* g, unsigned short* l) {
    __builtin_amdgcn_global_load_lds(
        (const __attribute__((address_space(1))) uint32_t*)g,
        (__attribute__((address_space(3))) uint32_t*)l, 16, 0, 0);
}

// ---------------- fp32 -> bf16 conversion ----------------
__global__ void cvt_f32_bf16(const float* __restrict__ src, unsigned short* __restrict__ dst, int n) {
    int i = (blockIdx.x * blockDim.x + threadIdx.x) * 4;
    int stride = gridDim.x * blockDim.x * 4;
    for (; i < n; i += stride) {
        float4 f = *(const float4*)(src + i);
        ushort4 o;
        o.x = f2b(f.x); o.y = f2b(f.y); o.z = f2b(f.z); o.w = f2b(f.w);
        *(ushort4*)(dst + i) = o;
    }
}

// ---------------- NT GEMM: C[M,N] = A[M,K] * W[N,K]^T, bf16 in, fp32 acc ----------------
// 128x128 tile, BK=32, 4 waves, global_load_lds width=16 staging (m97 structure),
// XOR chunk swizzle: LDS row r, chunk pos c holds global chunk c ^ ((r>>2)&3)
// -> ds_read_b128 fragment reads are 2-way (free) instead of 8-way.
template <bool BF16_OUT>
__global__ __launch_bounds__(256) void gemm_nt(
    const unsigned short* __restrict__ A, const unsigned short* __restrict__ W,
    void* __restrict__ Cv, int M, int N, int K) {
    __shared__ unsigned short As[128 * 32];
    __shared__ unsigned short Bs[128 * 32];
    const int bm = blockIdx.y * 128, bn = blockIdx.x * 128;
    const int tid = threadIdx.x;
    const int w = tid >> 6, lane = tid & 63;
    const int col = lane & 15, quad = lane >> 4;
    const int wm = (w & 1) * 64, wn = (w >> 1) * 64;
    const int sw = (quad ^ ((col >> 2) & 3)) * 8;  // swizzled chunk offset (shorts)

    // staging: thread t handles row r0 = t>>2 (and r0+64), source chunk swizzled
    const int r0 = tid >> 2;
    const int c0 = (tid & 3) ^ ((r0 >> 2) & 3);
    const unsigned short* Ap0 = A + (size_t)(bm + r0) * K + c0 * 8;
    const unsigned short* Ap1 = A + (size_t)(bm + r0 + 64) * K + c0 * 8;
    const unsigned short* Wp0 = W + (size_t)(bn + r0) * K + c0 * 8;
    const unsigned short* Wp1 = W + (size_t)(bn + r0 + 64) * K + c0 * 8;
    unsigned short* Asl0 = As + tid * 8;          // bytes: tid*16
    unsigned short* Asl1 = As + 2048 + tid * 8;
    unsigned short* Bsl0 = Bs + tid * 8;
    unsigned short* Bsl1 = Bs + 2048 + tid * 8;

    float4v acc[4][4];
    float4v zero4 = {0.f, 0.f, 0.f, 0.f};
#pragma unroll
    for (int i = 0; i < 4; i++)
#pragma unroll
        for (int j = 0; j < 4; j++) acc[i][j] = zero4;

    for (int k0 = 0; k0 < K; k0 += 32) {
        __syncthreads();
        gload_lds16(Ap0 + k0, Asl0);
        gload_lds16(Ap1 + k0, Asl1);
        gload_lds16(Wp0 + k0, Bsl0);
        gload_lds16(Wp1 + k0, Bsl1);
        __syncthreads();   // drains vmcnt -> staged data visible
        bf16x8 af[4], bf[4];
#pragma unroll
        for (int i = 0; i < 4; i++) af[i] = *(const bf16x8*)&As[(wm + i * 16 + col) * 32 + sw];
#pragma unroll
        for (int j = 0; j < 4; j++) bf[j] = *(const bf16x8*)&Bs[(wn + j * 16 + col) * 32 + sw];
#pragma unroll
        for (int i = 0; i < 4; i++)
#pragma unroll
            for (int j = 0; j < 4; j++)
                acc[i][j] = __builtin_amdgcn_mfma_f32_16x16x32_bf16(af[i], bf[j], acc[i][j], 0, 0, 0);
    }

#pragma unroll
    for (int i = 0; i < 4; i++) {
#pragma unroll
        for (int j = 0; j < 4; j++) {
#pragma unroll
            for (int r = 0; r < 4; r++) {
                int grow = bm + wm + i * 16 + quad * 4 + r;
                int gcol = bn + wn + j * 16 + col;
                if (BF16_OUT)
                    ((unsigned short*)Cv)[(size_t)grow * N + gcol] = f2b(acc[i][j][r]);
                else
                    ((float*)Cv)[(size_t)grow * N + gcol] = acc[i][j][r];
            }
        }
    }
}

// ---------------- RoPE + scatter; V written TRANSPOSED [b,kv][d][s] ----------------
__global__ void rope_scatter(const unsigned short* __restrict__ qkv,
                             const float* __restrict__ cosb, const float* __restrict__ sinb,
                             unsigned short* __restrict__ qa, unsigned short* __restrict__ ka,
                             unsigned short* __restrict__ vt) {
    int idx = blockIdx.x * blockDim.x + threadIdx.x;
    const int total = MROWS * NQKV;
    const int stride = gridDim.x * blockDim.x;
    for (; idx < total; idx += stride) {
        int row = idx / NQKV, o = idx - row * NQKV;
        int b = row >> 10, s = row & 1023;
        float x = b2f(qkv[idx]);
        if (o < H) {
            int kv = o >> 9, g = (o >> 6) & 7, d = o & 63;
            int po = (d < 32) ? idx + 32 : idx - 32;
            float partner = b2f(qkv[po]);
            float rot = (d < 32) ? -partner : partner;
            float y = x * cosb[s * 64 + d] + rot * sinb[s * 64 + d];
            int h = b * 64 + kv * 8 + g;
            qa[(size_t)h * (S * D) + s * 64 + d] = f2b(y);
        } else if (o < H + 512) {
            int o2 = o - H;
            int kv = o2 >> 6, d = o2 & 63;
            int po = (d < 32) ? idx + 32 : idx - 32;
            float partner = b2f(qkv[po]);
            float rot = (d < 32) ? -partner : partner;
            float y = x * cosb[s * 64 + d] + rot * sinb[s * 64 + d];
            ka[(size_t)(b * NKV + kv) * (S * D) + s * 64 + d] = f2b(y);
        } else {
            int o2 = o - H - 512;
            int kv = o2 >> 6, d = o2 & 63;
            vt[(size_t)(b * NKV + kv) * (D * S) + (size_t)d * S + s] = qkv[idx];
        }
    }
}

// ---------------- Flash attention, pair-balanced causal tiles ----------------
// block = (pair p, head h). Processes Q tiles qt=p then qt=15-p: exactly 17
// K-tile iterations per block -> uniform work, no causal tail.
__global__ __launch_bounds__(256) void attn_kernel(
    const unsigned short* __restrict__ qa, const unsigned short* __restrict__ ka,
    const unsigned short* __restrict__ vt, unsigned short* __restrict__ out) {
    __shared__ unsigned short Ks[64 * 72];
    __shared__ unsigned short Vs[64 * 72];   // V^T tile: [d][key]
    __shared__ unsigned short Ps[4 * 16 * 72];
    const int p = blockIdx.x;   // 0..7
    const int h = blockIdx.y;   // 0..127
    const int b = h >> 6, kvh = (h >> 3) & 7;
    const int tid = threadIdx.x, w = tid >> 6, lane = tid & 63;
    const int col = lane & 15, quad = lane >> 4;
    const unsigned short* Kg = ka + (size_t)(b * NKV + kvh) * (S * D);
    const unsigned short* Vg = vt + (size_t)(b * NKV + kvh) * (D * S);
    const int srow = tid >> 3, scc = (tid & 7) * 8;
    const int hcol = (h & 63) * 64;
    float4v zero4 = {0.f, 0.f, 0.f, 0.f};

#pragma unroll
    for (int part = 0; part < 2; part++) {
        const int qt = part ? (15 - p) : p;
        const int qb = qt * 64;
        const unsigned short* Q = qa + (size_t)h * (S * D) + (size_t)qb * D;

        bf16x8 aq[2];
#pragma unroll
        for (int c = 0; c < 2; c++)
            aq[c] = *(const bf16x8*)&Q[(w * 16 + col) * 64 + c * 32 + quad * 8];

        float m_run[4], l_run[4];
        float4v o_acc[4];
#pragma unroll
        for (int r = 0; r < 4; r++) { m_run[r] = -1e30f; l_run[r] = 0.f; }
#pragma unroll
        for (int dg = 0; dg < 4; dg++) o_acc[dg] = zero4;

        for (int kt = 0; kt <= qt; kt++) {
            const int kb = kt * 64;
            __syncthreads();   // protect Ks/Vs from overwrite while prior PV pending
            *(short8*)&Ks[srow * 72 + scc]        = *(const short8*)&Kg[(kb + srow) * 64 + scc];
            *(short8*)&Ks[(srow + 32) * 72 + scc] = *(const short8*)&Kg[(kb + srow + 32) * 64 + scc];
            *(short8*)&Vs[srow * 72 + scc]        = *(const short8*)&Vg[(size_t)srow * S + kb + scc];
            *(short8*)&Vs[(srow + 32) * 72 + scc] = *(const short8*)&Vg[(size_t)(srow + 32) * S + kb + scc];
            __syncthreads();

            // scores: Q(16x64) x K_tile^T -> 16x64 per wave
            float4v sc[4];
#pragma unroll
            for (int n16 = 0; n16 < 4; n16++) {
                bf16x8 bk0 = *(const bf16x8*)&Ks[(n16 * 16 + col) * 72 + quad * 8];
                bf16x8 bk1 = *(const bf16x8*)&Ks[(n16 * 16 + col) * 72 + 32 + quad * 8];
                float4v a = __builtin_amdgcn_mfma_f32_16x16x32_bf16(aq[0], bk0, zero4, 0, 0, 0);
                sc[n16] = __builtin_amdgcn_mfma_f32_16x16x32_bf16(aq[1], bk1, a, 0, 0, 0);
            }
            // scale + causal mask
#pragma unroll
            for (int n16 = 0; n16 < 4; n16++) {
                int key = kb + n16 * 16 + col;
#pragma unroll
                for (int r = 0; r < 4; r++) {
                    int qrow = qb + w * 16 + quad * 4 + r;
                    float sv = sc[n16][r] * 0.125f;
                    sc[n16][r] = (key <= qrow) ? sv : -1e30f;
                }
            }
            // online softmax (rows live across the 16 lanes of each quad)
#pragma unroll
            for (int r = 0; r < 4; r++) {
                float mx = fmaxf(fmaxf(sc[0][r], sc[1][r]), fmaxf(sc[2][r], sc[3][r]));
#pragma unroll
                for (int off = 1; off < 16; off <<= 1) mx = fmaxf(mx, __shfl_xor(mx, off));
                float mnew = fmaxf(m_run[r], mx);
                float alpha = __expf(m_run[r] - mnew);
                float rsum = 0.f;
#pragma unroll
                for (int n16 = 0; n16 < 4; n16++) {
                    float pr = __expf(sc[n16][r] - mnew);
                    sc[n16][r] = pr;
                    rsum += pr;
                }
#pragma unroll
                for (int off = 1; off < 16; off <<= 1) rsum += __shfl_xor(rsum, off);
                l_run[r] = l_run[r] * alpha + rsum;
                m_run[r] = mnew;
#pragma unroll
                for (int dg = 0; dg < 4; dg++) o_acc[dg][r] *= alpha;
            }
            // P (C/D layout) -> LDS; wave-private region, NO barrier needed
#pragma unroll
            for (int n16 = 0; n16 < 4; n16++)
#pragma unroll
                for (int r = 0; r < 4; r++)
                    Ps[w * 1152 + (quad * 4 + r) * 72 + n16 * 16 + col] = f2b(sc[n16][r]);
            // PV: P(16x64) x V(64x64)
            bf16x8 ap[2];
#pragma unroll
            for (int c = 0; c < 2; c++)
                ap[c] = *(const bf16x8*)&Ps[w * 1152 + col * 72 + c * 32 + quad * 8];
#pragma unroll
            for (int dg = 0; dg < 4; dg++) {
                bf16x8 bv0 = *(const bf16x8*)&Vs[(dg * 16 + col) * 72 + quad * 8];
                bf16x8 bv1 = *(const bf16x8*)&Vs[(dg * 16 + col) * 72 + 32 + quad * 8];
                float4v t = __builtin_amdgcn_mfma_f32_16x16x32_bf16(ap[0], bv0, o_acc[dg], 0, 0, 0);
                o_acc[dg] = __builtin_amdgcn_mfma_f32_16x16x32_bf16(ap[1], bv1, t, 0, 0, 0);
            }
        }
        // epilogue: normalize and store
#pragma unroll
        for (int r = 0; r < 4; r++) {
            float inv = 1.f / l_run[r];
            int grow = b * S + qb + w * 16 + quad * 4 + r;
#pragma unroll
            for (int dg = 0; dg < 4; dg++)
                out[(size_t)grow * H + hcol + dg * 16 + col] = f2b(o_acc[dg][r] * inv);
        }
    }
}

extern "C" void kernel_launch(void* const* d_in, const int* in_sizes, int n_in,
                              void* d_out, int out_size, void* d_ws, size_t ws_size,
                              hipStream_t stream) {
    const float* hs   = (const float*)d_in[0];
    // d_in[1] alibi, d_in[2] attention_mask: unused by reference (zeros)
    const float* cosb = (const float*)d_in[3];
    const float* sinb = (const float*)d_in[4];
    const float* wq   = (const float*)d_in[5];
    const float* wk   = (const float*)d_in[6];
    const float* wv   = (const float*)d_in[7];
    const float* wd   = (const float*)d_in[8];

    char* p = (char*)d_ws;
    auto alloc = [&](size_t bytes) { char* r = p; p += (bytes + 255) & ~(size_t)255; return r; };
    unsigned short* wqkv_b = (unsigned short*)alloc((size_t)NQKV * H * 2);
    unsigned short* wd_b   = (unsigned short*)alloc((size_t)H * H * 2);
    unsigned short* qkv    = (unsigned short*)alloc((size_t)MROWS * NQKV * 2);
    unsigned short* qa     = (unsigned short*)alloc((size_t)BB * NH * S * D * 2);
    unsigned short* ka     = (unsigned short*)alloc((size_t)BB * NKV * S * D * 2);
    unsigned short* vt     = (unsigned short*)alloc((size_t)BB * NKV * S * D * 2);
    unsigned short* hs_b   = (unsigned short*)alloc((size_t)MROWS * H * 2);
    unsigned short* ao     = hs_b;  // alias: hs_b consumed by GEMM1 before attn writes ao

    cvt_f32_bf16<<<2048, 256, 0, stream>>>(hs, hs_b, MROWS * H);
    cvt_f32_bf16<<<2048, 256, 0, stream>>>(wq, wqkv_b, H * H);
    cvt_f32_bf16<<<1024, 256, 0, stream>>>(wk, wqkv_b + (size_t)H * H, 512 * H);
    cvt_f32_bf16<<<1024, 256, 0, stream>>>(wv, wqkv_b + (size_t)H * H + (size_t)512 * H, 512 * H);
    cvt_f32_bf16<<<2048, 256, 0, stream>>>(wd, wd_b, H * H);

    gemm_nt<true><<<dim3(NQKV / 128, MROWS / 128), 256, 0, stream>>>(hs_b, wqkv_b, qkv, MROWS, NQKV, H);
    rope_scatter<<<4096, 256, 0, stream>>>(qkv, cosb, sinb, qa, ka, vt);
    attn_kernel<<<dim3(8, 128), 256, 0, stream>>>(qa, ka, vt, ao);
    gemm_nt<false><<<dim3(H / 128, MROWS / 128), 256, 0, stream>>>(ao, wd_b, d_out, MROWS, H, H);
}

// Round 3
// 514.326 us; speedup vs baseline: 1.2403x; 1.0195x over previous
//
#include <hip/hip_runtime.h>
#include <hip/hip_bf16.h>
#include <cstdint>

typedef short short8 __attribute__((ext_vector_type(8)));
typedef __bf16 bf16x8 __attribute__((ext_vector_type(8)));
typedef float float4v __attribute__((ext_vector_type(4)));
typedef float float16v __attribute__((ext_vector_type(16)));

#define NKV 8
#define G 8
#define D 64
#define NH 64
#define BB 2
#define S 1024
#define H 4096
#define MROWS (BB*S)         // 2048
#define NQKV (H + 2*NKV*D)   // 5120

__device__ __forceinline__ unsigned short f2b(float f) {
    union { float f; uint32_t u; } v; v.f = f;
    uint32_t u = v.u;
    uint32_t r = (u + 0x7FFFu + ((u >> 16) & 1u)) >> 16;
    return (unsigned short)r;
}
__device__ __forceinline__ float b2f(unsigned short b) {
    union { float f; uint32_t u; } v; v.u = ((uint32_t)b) << 16;
    return v.f;
}

__device__ __forceinline__ void gload_lds16(const unsigned short* g, unsigned short* l) {
    __builtin_amdgcn_global_load_lds(
        (const __attribute__((address_space(1))) uint32_t*)g,
        (__attribute__((address_space(3))) uint32_t*)l, 16, 0, 0);
}

// ---------------- fused fp32 -> bf16 conversion for all 5 tensors ----------------
__global__ void cvt_all(const float* __restrict__ hs, const float* __restrict__ wq,
                        const float* __restrict__ wk, const float* __restrict__ wv,
                        const float* __restrict__ wd,
                        unsigned short* __restrict__ hs_b, unsigned short* __restrict__ wqkv_b,
                        unsigned short* __restrict__ wd_b) {
    const size_t N0 = (size_t)MROWS * H;      // 8388608  hs
    const size_t N1 = (size_t)H * H;          // 16777216 wq
    const size_t N2 = (size_t)512 * H;        // 2097152  wk
    const size_t N3 = (size_t)512 * H;        // 2097152  wv
    const size_t N4 = (size_t)H * H;          // 16777216 wd
    const size_t total4 = (N0 + N1 + N2 + N3 + N4) / 4;
    size_t i = (size_t)blockIdx.x * blockDim.x + threadIdx.x;
    const size_t stride = (size_t)gridDim.x * blockDim.x;
    for (; i < total4; i += stride) {
        size_t e = i * 4;
        const float* s; unsigned short* d;
        if (e < N0)                { s = hs + e;                  d = hs_b + e; }
        else if (e < N0+N1)        { s = wq + (e-N0);             d = wqkv_b + (e-N0); }
        else if (e < N0+N1+N2)     { s = wk + (e-N0-N1);          d = wqkv_b + N1 + (e-N0-N1); }
        else if (e < N0+N1+N2+N3)  { s = wv + (e-N0-N1-N2);       d = wqkv_b + N1+N2 + (e-N0-N1-N2); }
        else                       { s = wd + (e-N0-N1-N2-N3);    d = wd_b + (e-N0-N1-N2-N3); }
        float4 f = *(const float4*)s;
        ushort4 o;
        o.x = f2b(f.x); o.y = f2b(f.y); o.z = f2b(f.z); o.w = f2b(f.w);
        *(ushort4*)d = o;
    }
}

// ---------------- NT GEMM: C[M,N] = A[M,K] * W[N,K]^T ----------------
// 128x128 tile, BK=32, 4 waves (2x2 of 64x64), mfma_f32_32x32x16_bf16 (2x2 of 32x32 per wave),
// global_load_lds width=16 staging, XOR chunk swizzle, pointer-bumped K loop.
template <bool BF16_OUT>
__global__ __launch_bounds__(256) void gemm_nt(
    const unsigned short* __restrict__ A, const unsigned short* __restrict__ W,
    void* __restrict__ Cv, int M, int N, int K) {
    __shared__ unsigned short As[128 * 32];
    __shared__ unsigned short Bs[128 * 32];
    const int bm = blockIdx.y * 128, bn = blockIdx.x * 128;
    const int tid = threadIdx.x;
    const int w = tid >> 6, lane = tid & 63;
    const int n32 = lane & 31, khalf = lane >> 5;
    const int wm = (w & 1) * 64, wn = (w >> 1) * 64;

    // staging: thread t -> row r0=t>>2 (and r0+64), LDS chunk pos t&3, source chunk swizzled
    const int r0 = tid >> 2;
    const int c0 = (tid & 3) ^ ((r0 >> 2) & 3);
    const unsigned short* pA0 = A + (size_t)(bm + r0) * K + c0 * 8;
    const unsigned short* pA1 = A + (size_t)(bm + r0 + 64) * K + c0 * 8;
    const unsigned short* pW0 = W + (size_t)(bn + r0) * K + c0 * 8;
    const unsigned short* pW1 = W + (size_t)(bn + r0 + 64) * K + c0 * 8;
    unsigned short* Asl0 = As + tid * 8;
    unsigned short* Asl1 = As + 2048 + tid * 8;
    unsigned short* Bsl0 = Bs + tid * 8;
    unsigned short* Bsl1 = Bs + 2048 + tid * 8;

    // loop-invariant fragment pointers: [mg or ng][k-step s]
    const unsigned short* aP[2][2];
    const unsigned short* bP[2][2];
#pragma unroll
    for (int g = 0; g < 2; g++)
#pragma unroll
        for (int s = 0; s < 2; s++) {
            int cp = ((s << 1) | khalf) ^ ((n32 >> 2) & 3);
            aP[g][s] = &As[(wm + g * 32 + n32) * 32 + cp * 8];
            bP[g][s] = &Bs[(wn + g * 32 + n32) * 32 + cp * 8];
        }

    float16v acc[2][2] = {};

    const int iters = K >> 5;
    for (int it = 0; it < iters; ++it) {
        __syncthreads();
        gload_lds16(pA0, Asl0);
        gload_lds16(pA1, Asl1);
        gload_lds16(pW0, Bsl0);
        gload_lds16(pW1, Bsl1);
        pA0 += 32; pA1 += 32; pW0 += 32; pW1 += 32;
        __syncthreads();
        bf16x8 af[2][2], bf[2][2];
#pragma unroll
        for (int g = 0; g < 2; g++)
#pragma unroll
            for (int s = 0; s < 2; s++) {
                af[g][s] = *(const bf16x8*)aP[g][s];
                bf[g][s] = *(const bf16x8*)bP[g][s];
            }
#pragma unroll
        for (int s = 0; s < 2; s++)
#pragma unroll
            for (int mg = 0; mg < 2; mg++)
#pragma unroll
                for (int ng = 0; ng < 2; ng++)
                    acc[mg][ng] = __builtin_amdgcn_mfma_f32_32x32x16_bf16(
                        af[mg][s], bf[ng][s], acc[mg][ng], 0, 0, 0);
    }

    // epilogue: C/D layout (verified): col = lane&31, row = (reg&3) + 8*(reg>>2) + 4*(lane>>5)
#pragma unroll
    for (int mg = 0; mg < 2; mg++) {
#pragma unroll
        for (int ng = 0; ng < 2; ng++) {
            int gcol = bn + wn + ng * 32 + n32;
#pragma unroll
            for (int reg = 0; reg < 16; reg++) {
                int grow = bm + wm + mg * 32 + (reg & 3) + 8 * (reg >> 2) + 4 * khalf;
                if (BF16_OUT)
                    ((unsigned short*)Cv)[(size_t)grow * N + gcol] = f2b(acc[mg][ng][reg]);
                else
                    ((float*)Cv)[(size_t)grow * N + gcol] = acc[mg][ng][reg];
            }
        }
    }
}

// ---------------- RoPE + scatter; V written TRANSPOSED [b,kv][d][s] ----------------
__global__ void rope_scatter(const unsigned short* __restrict__ qkv,
                             const float* __restrict__ cosb, const float* __restrict__ sinb,
                             unsigned short* __restrict__ qa, unsigned short* __restrict__ ka,
                             unsigned short* __restrict__ vt) {
    int idx = blockIdx.x * blockDim.x + threadIdx.x;
    const int total = MROWS * NQKV;
    const int stride = gridDim.x * blockDim.x;
    for (; idx < total; idx += stride) {
        int row = idx / NQKV, o = idx - row * NQKV;
        int b = row >> 10, s = row & 1023;
        float x = b2f(qkv[idx]);
        if (o < H) {
            int kv = o >> 9, g = (o >> 6) & 7, d = o & 63;
            int po = (d < 32) ? idx + 32 : idx - 32;
            float partner = b2f(qkv[po]);
            float rot = (d < 32) ? -partner : partner;
            float y = x * cosb[s * 64 + d] + rot * sinb[s * 64 + d];
            int h = b * 64 + kv * 8 + g;
            qa[(size_t)h * (S * D) + s * 64 + d] = f2b(y);
        } else if (o < H + 512) {
            int o2 = o - H;
            int kv = o2 >> 6, d = o2 & 63;
            int po = (d < 32) ? idx + 32 : idx - 32;
            float partner = b2f(qkv[po]);
            float rot = (d < 32) ? -partner : partner;
            float y = x * cosb[s * 64 + d] + rot * sinb[s * 64 + d];
            ka[(size_t)(b * NKV + kv) * (S * D) + s * 64 + d] = f2b(y);
        } else {
            int o2 = o - H - 512;
            int kv = o2 >> 6, d = o2 & 63;
            vt[(size_t)(b * NKV + kv) * (D * S) + (size_t)d * S + s] = qkv[idx];
        }
    }
}

// ---------------- Flash attention, pair-balanced, 2 query heads per block ----------------
// blockIdx.x = pair p (0..7): Q tiles qt=p and 15-p -> 17 K-tiles/block.
// blockIdx.y = (b, kvh, gpair): 2*8*4 = 64. Heads h0 = b*64+kvh*8+gpair*2, h1 = h0+1
// share the staged K/V tile -> staging & barriers per MFMA halved.
__global__ __launch_bounds__(256) void attn_kernel(
    const unsigned short* __restrict__ qa, const unsigned short* __restrict__ ka,
    const unsigned short* __restrict__ vt, unsigned short* __restrict__ out) {
    __shared__ unsigned short Ks[64 * 72];
    __shared__ unsigned short Vs[64 * 72];   // V^T tile: [d][key]
    __shared__ unsigned short Ps[4 * 16 * 72];
    const int p = blockIdx.x;
    const int yy = blockIdx.y;
    const int b = yy >> 5, kvh = (yy >> 2) & 7, gp = yy & 3;
    const int h0 = b * 64 + kvh * 8 + gp * 2;
    const int tid = threadIdx.x, w = tid >> 6, lane = tid & 63;
    const int col = lane & 15, quad = lane >> 4;
    const unsigned short* Kg = ka + (size_t)(b * NKV + kvh) * (S * D);
    const unsigned short* Vg = vt + (size_t)(b * NKV + kvh) * (D * S);
    const int srow = tid >> 3, scc = (tid & 7) * 8;
    float4v zero4 = {0.f, 0.f, 0.f, 0.f};
    const float SC2 = 0.125f * 1.44269504089f;  // fold 1/sqrt(D) and log2(e): exp2 domain

#pragma unroll
    for (int part = 0; part < 2; part++) {
        const int qt = part ? (15 - p) : p;
        const int qb = qt * 64;

        bf16x8 aq[2][2];
#pragma unroll
        for (int hd = 0; hd < 2; hd++)
#pragma unroll
            for (int c = 0; c < 2; c++)
                aq[hd][c] = *(const bf16x8*)&qa[(size_t)(h0 + hd) * (S * D) + (size_t)qb * D
                                               + (w * 16 + col) * 64 + c * 32 + quad * 8];

        float m_run[2][4], l_run[2][4];
        float4v o_acc[2][4];
#pragma unroll
        for (int hd = 0; hd < 2; hd++) {
#pragma unroll
            for (int r = 0; r < 4; r++) { m_run[hd][r] = -1e30f; l_run[hd][r] = 0.f; }
#pragma unroll
            for (int dg = 0; dg < 4; dg++) o_acc[hd][dg] = zero4;
        }

        for (int kt = 0; kt <= qt; kt++) {
            const int kb = kt * 64;
            __syncthreads();
            *(short8*)&Ks[srow * 72 + scc]        = *(const short8*)&Kg[(kb + srow) * 64 + scc];
            *(short8*)&Ks[(srow + 32) * 72 + scc] = *(const short8*)&Kg[(kb + srow + 32) * 64 + scc];
            *(short8*)&Vs[srow * 72 + scc]        = *(const short8*)&Vg[(size_t)srow * S + kb + scc];
            *(short8*)&Vs[(srow + 32) * 72 + scc] = *(const short8*)&Vg[(size_t)(srow + 32) * S + kb + scc];
            __syncthreads();

#pragma unroll
            for (int hd = 0; hd < 2; hd++) {
                // scores: Q(16x64) x K_tile^T -> 16x64 per wave
                float4v sc[4];
#pragma unroll
                for (int n16 = 0; n16 < 4; n16++) {
                    bf16x8 bk0 = *(const bf16x8*)&Ks[(n16 * 16 + col) * 72 + quad * 8];
                    bf16x8 bk1 = *(const bf16x8*)&Ks[(n16 * 16 + col) * 72 + 32 + quad * 8];
                    float4v a = __builtin_amdgcn_mfma_f32_16x16x32_bf16(aq[hd][0], bk0, zero4, 0, 0, 0);
                    sc[n16] = __builtin_amdgcn_mfma_f32_16x16x32_bf16(aq[hd][1], bk1, a, 0, 0, 0);
                }
#pragma unroll
                for (int n16 = 0; n16 < 4; n16++) {
                    int key = kb + n16 * 16 + col;
#pragma unroll
                    for (int r = 0; r < 4; r++) {
                        int qrow = qb + w * 16 + quad * 4 + r;
                        float sv = sc[n16][r] * SC2;
                        sc[n16][r] = (key <= qrow) ? sv : -1e30f;
                    }
                }
#pragma unroll
                for (int r = 0; r < 4; r++) {
                    float mx = fmaxf(fmaxf(sc[0][r], sc[1][r]), fmaxf(sc[2][r], sc[3][r]));
#pragma unroll
                    for (int off = 1; off < 16; off <<= 1) mx = fmaxf(mx, __shfl_xor(mx, off));
                    float mnew = fmaxf(m_run[hd][r], mx);
                    float alpha = __builtin_amdgcn_exp2f(m_run[hd][r] - mnew);
                    float rsum = 0.f;
#pragma unroll
                    for (int n16 = 0; n16 < 4; n16++) {
                        float pr = __builtin_amdgcn_exp2f(sc[n16][r] - mnew);
                        sc[n16][r] = pr;
                        rsum += pr;
                    }
#pragma unroll
                    for (int off = 1; off < 16; off <<= 1) rsum += __shfl_xor(rsum, off);
                    l_run[hd][r] = l_run[hd][r] * alpha + rsum;
                    m_run[hd][r] = mnew;
#pragma unroll
                    for (int dg = 0; dg < 4; dg++) o_acc[hd][dg][r] *= alpha;
                }
                // P (C/D layout) -> wave-private LDS, no barrier
#pragma unroll
                for (int n16 = 0; n16 < 4; n16++)
#pragma unroll
                    for (int r = 0; r < 4; r++)
                        Ps[w * 1152 + (quad * 4 + r) * 72 + n16 * 16 + col] = f2b(sc[n16][r]);
                bf16x8 ap[2];
#pragma unroll
                for (int c = 0; c < 2; c++)
                    ap[c] = *(const bf16x8*)&Ps[w * 1152 + col * 72 + c * 32 + quad * 8];
#pragma unroll
                for (int dg = 0; dg < 4; dg++) {
                    bf16x8 bv0 = *(const bf16x8*)&Vs[(dg * 16 + col) * 72 + quad * 8];
                    bf16x8 bv1 = *(const bf16x8*)&Vs[(dg * 16 + col) * 72 + 32 + quad * 8];
                    float4v t = __builtin_amdgcn_mfma_f32_16x16x32_bf16(ap[0], bv0, o_acc[hd][dg], 0, 0, 0);
                    o_acc[hd][dg] = __builtin_amdgcn_mfma_f32_16x16x32_bf16(ap[1], bv1, t, 0, 0, 0);
                }
            }
        }
#pragma unroll
        for (int hd = 0; hd < 2; hd++) {
            const int hcol = ((h0 + hd) & 63) * 64;
#pragma unroll
            for (int r = 0; r < 4; r++) {
                float inv = 1.f / l_run[hd][r];
                int grow = b * S + qb + w * 16 + quad * 4 + r;
#pragma unroll
                for (int dg = 0; dg < 4; dg++)
                    out[(size_t)grow * H + hcol + dg * 16 + col] = f2b(o_acc[hd][dg][r] * inv);
            }
        }
    }
}

extern "C" void kernel_launch(void* const* d_in, const int* in_sizes, int n_in,
                              void* d_out, int out_size, void* d_ws, size_t ws_size,
                              hipStream_t stream) {
    const float* hs   = (const float*)d_in[0];
    // d_in[1] alibi, d_in[2] attention_mask: unused by reference (zeros)
    const float* cosb = (const float*)d_in[3];
    const float* sinb = (const float*)d_in[4];
    const float* wq   = (const float*)d_in[5];
    const float* wk   = (const float*)d_in[6];
    const float* wv   = (const float*)d_in[7];
    const float* wd   = (const float*)d_in[8];

    char* p = (char*)d_ws;
    auto alloc = [&](size_t bytes) { char* r = p; p += (bytes + 255) & ~(size_t)255; return r; };
    unsigned short* wqkv_b = (unsigned short*)alloc((size_t)NQKV * H * 2);
    unsigned short* wd_b   = (unsigned short*)alloc((size_t)H * H * 2);
    unsigned short* qkv    = (unsigned short*)alloc((size_t)MROWS * NQKV * 2);
    unsigned short* qa     = (unsigned short*)alloc((size_t)BB * NH * S * D * 2);
    unsigned short* ka     = (unsigned short*)alloc((size_t)BB * NKV * S * D * 2);
    unsigned short* vt     = (unsigned short*)alloc((size_t)BB * NKV * S * D * 2);
    unsigned short* hs_b   = (unsigned short*)alloc((size_t)MROWS * H * 2);
    unsigned short* ao     = hs_b;  // alias: hs_b consumed by GEMM1 before attn writes ao

    cvt_all<<<4096, 256, 0, stream>>>(hs, wq, wk, wv, wd, hs_b, wqkv_b, wd_b);

    gemm_nt<true><<<dim3(NQKV / 128, MROWS / 128), 256, 0, stream>>>(hs_b, wqkv_b, qkv, MROWS, NQKV, H);
    rope_scatter<<<4096, 256, 0, stream>>>(qkv, cosb, sinb, qa, ka, vt);
    attn_kernel<<<dim3(8, 64), 256, 0, stream>>>(qa, ka, vt, ao);
    gemm_nt<false><<<dim3(H / 128, MROWS / 128), 256, 0, stream>>>(ao, wd_b, d_out, MROWS, H, H);
}